// Round 1
// baseline (1056.600 us; speedup 1.0000x reference)
//
#include <hip/hip_runtime.h>
#include <cstdint>
#include <cstddef>

typedef _Float16 f16;
typedef __attribute__((ext_vector_type(8))) f16 f16x8;
typedef __attribute__((ext_vector_type(4))) f16 f16x4;
typedef __attribute__((ext_vector_type(4))) float f32x4;

#define M_TOK 8192
#define DDIM 1024
#define HDIM 4096
#define NEXP 4

// async global->LDS, 16B per lane. LDS dest is wave-uniform base + lane*16;
// our staging mapping is exactly contiguous per lane, so this is safe.
__device__ __forceinline__ void async_copy16(const void* g, void* s) {
    __builtin_amdgcn_global_load_lds((__attribute__((address_space(1))) void*)g,
                                     (__attribute__((address_space(3))) void*)s,
                                     16, 0, 0);
}

// ---------------- Router: logits -> softmax -> top2 -> renorm --------------
// one wave per token; top2-of-softmax + renorm == softmax over top-2 logits.
__global__ __launch_bounds__(256) void router_kernel(
    const float* __restrict__ x, const float* __restrict__ Wr,
    float* __restrict__ wts, float* __restrict__ outF, int aux_idx) {
    __shared__ float wr_s[DDIM * NEXP];
    for (int i = threadIdx.x; i < DDIM * NEXP; i += 256) wr_s[i] = Wr[i];
    __syncthreads();
    const int wave = threadIdx.x >> 6, lane = threadIdx.x & 63;
    const int t = blockIdx.x * 4 + wave;
    float a0 = 0.f, a1 = 0.f, a2 = 0.f, a3 = 0.f;
    const float* xr = x + (size_t)t * DDIM;
    for (int i = 0; i < DDIM; i += 256) {
        const int d = i + lane * 4;
        const float4 v = *(const float4*)(xr + d);
        const float* w0 = &wr_s[d * 4];
        a0 += v.x * w0[0] + v.y * w0[4] + v.z * w0[8]  + v.w * w0[12];
        a1 += v.x * w0[1] + v.y * w0[5] + v.z * w0[9]  + v.w * w0[13];
        a2 += v.x * w0[2] + v.y * w0[6] + v.z * w0[10] + v.w * w0[14];
        a3 += v.x * w0[3] + v.y * w0[7] + v.z * w0[11] + v.w * w0[15];
    }
    for (int off = 32; off > 0; off >>= 1) {
        a0 += __shfl_xor(a0, off, 64);
        a1 += __shfl_xor(a1, off, 64);
        a2 += __shfl_xor(a2, off, 64);
        a3 += __shfl_xor(a3, off, 64);
    }
    if (lane == 0) {
        float lg[4] = {a0, a1, a2, a3};
        int i1 = 0;
        for (int e = 1; e < 4; ++e) if (lg[e] > lg[i1]) i1 = e;
        int i2 = -1;
        for (int e = 0; e < 4; ++e) {
            if (e == i1) continue;
            if (i2 < 0 || lg[e] > lg[i2]) i2 = e;
        }
        const float w1 = 1.0f / (1.0f + expf(lg[i2] - lg[i1]));
        float w[4] = {0.f, 0.f, 0.f, 0.f};
        w[i1] = w1; w[i2] = 1.0f - w1;
        float* o = wts + (size_t)t * 4;
        o[0] = w[0]; o[1] = w[1]; o[2] = w[2]; o[3] = w[3];
    }
    if (blockIdx.x == 0 && threadIdx.x == 0 && aux_idx >= 0) outF[aux_idx] = 0.0f;
}

// ---------------- fp32 -> f16 elementwise (x) ------------------------------
__global__ __launch_bounds__(256) void convert_f16_kernel(
    const float* __restrict__ in, f16* __restrict__ out, int n4) {
    const int i = blockIdx.x * 256 + threadIdx.x;
    if (i < n4) {
        const float4 v = ((const float4*)in)[i];
        f16x4 o = {(f16)v.x, (f16)v.y, (f16)v.z, (f16)v.w};
        ((f16x4*)out)[i] = o;
    }
}

// ---------------- fp32 [R][C] -> f16 [C][R] transpose ----------------------
__global__ __launch_bounds__(256) void transpose_f16_kernel(
    const float* __restrict__ in, f16* __restrict__ out, int R, int C) {
    __shared__ float tile[32][33];
    const int c0 = blockIdx.x * 32, r0 = blockIdx.y * 32;
    const int tx = threadIdx.x & 31;
    const int ty = threadIdx.x >> 5;  // 0..7
#pragma unroll
    for (int i = 0; i < 32; i += 8)
        tile[ty + i][tx] = in[(size_t)(r0 + ty + i) * C + c0 + tx];
    __syncthreads();
#pragma unroll
    for (int i = 0; i < 32; i += 8)
        out[(size_t)(c0 + ty + i) * R + r0 + tx] = (f16)tile[tx][ty + i];
}

// ---------------- m97-style 128x128 GEMM, A[M][K] x BT[N][K] ---------------
// MODE 0: outH = relu(acc + bias)  (f16, ld = N)
// MODE 1: outF (+)= wts[m][expert] * (acc + bias)  (fp32, ld = N)
template <int MODE>
__global__ __launch_bounds__(256) void gemm_kernel(
    const f16* __restrict__ A, const f16* __restrict__ BT,
    int M, int N, int K,
    const float* __restrict__ bias,
    f16* __restrict__ outH, float* __restrict__ outF,
    const float* __restrict__ wts, int expert, int first) {
    __shared__ __align__(16) f16 As[128 * 64];
    __shared__ __align__(16) f16 Bs[128 * 64];
    const int tid = threadIdx.x;
    const int wave = tid >> 6, lane = tid & 63;
    const int wm = wave >> 1, wn = wave & 1;
    const int quad = lane >> 4, l16 = lane & 15;
    const int m0 = blockIdx.y * 128, n0 = blockIdx.x * 128;

    f32x4 acc[4][4] = {};

    // staging mapping: round r, chunk c = r*256+tid -> row c>>3, 16B col (c&7)*16
    const int crow = tid >> 3;          // 32 rows per round
    const int kel = (tid & 7) * 8;      // element offset within 64-wide k slice
    const f16* ga = A + (size_t)(m0 + crow) * K + kel;
    const f16* gb = BT + (size_t)(n0 + crow) * K + kel;

    for (int k0 = 0; k0 < K; k0 += 64) {
#pragma unroll
        for (int r = 0; r < 4; ++r)
            async_copy16(ga + (size_t)(r * 32) * K + k0, &As[(r * 256 + tid) * 8]);
#pragma unroll
        for (int r = 0; r < 4; ++r)
            async_copy16(gb + (size_t)(r * 32) * K + k0, &Bs[(r * 256 + tid) * 8]);
        __syncthreads();  // compiler emits vmcnt(0) drain before barrier
#pragma unroll
        for (int kk = 0; kk < 64; kk += 32) {
            f16x8 af[4], bf[4];
#pragma unroll
            for (int i = 0; i < 4; ++i)
                af[i] = *(const f16x8*)&As[(wm * 64 + i * 16 + l16) * 64 + kk + quad * 8];
#pragma unroll
            for (int j = 0; j < 4; ++j)
                bf[j] = *(const f16x8*)&Bs[(wn * 64 + j * 16 + l16) * 64 + kk + quad * 8];
#pragma unroll
            for (int i = 0; i < 4; ++i)
#pragma unroll
                for (int j = 0; j < 4; ++j)
                    acc[i][j] = __builtin_amdgcn_mfma_f32_16x16x32_f16(af[i], bf[j], acc[i][j], 0, 0, 0);
        }
        __syncthreads();
    }

    // epilogue: C/D layout col = lane&15, row = quad*4 + reg (m89/m91-verified)
#pragma unroll
    for (int i = 0; i < 4; ++i) {
        const int mbase = m0 + wm * 64 + i * 16 + quad * 4;
#pragma unroll
        for (int j = 0; j < 4; ++j) {
            const int n = n0 + wn * 64 + j * 16 + l16;
            const float bv = bias[n];
#pragma unroll
            for (int r = 0; r < 4; ++r) {
                const int m = mbase + r;
                float v = acc[i][j][r] + bv;
                if (MODE == 0) {
                    v = v > 0.0f ? v : 0.0f;
                    outH[(size_t)m * N + n] = (f16)v;
                } else {
                    const float w = wts[m * 4 + expert];
                    const size_t o = (size_t)m * N + n;
                    if (first) outF[o] = w * v;
                    else outF[o] += w * v;
                }
            }
        }
    }
}

extern "C" void kernel_launch(void* const* d_in, const int* in_sizes, int n_in,
                              void* d_out, int out_size, void* d_ws, size_t ws_size,
                              hipStream_t stream) {
    (void)in_sizes; (void)n_in; (void)ws_size;
    const float* x  = (const float*)d_in[0];
    const float* Wr = (const float*)d_in[1];
    const float* W1 = (const float*)d_in[2];
    const float* b1 = (const float*)d_in[3];
    const float* W2 = (const float*)d_in[4];
    const float* b2 = (const float*)d_in[5];
    float* out = (float*)d_out;

    // workspace layout (total ~96.2 MB):
    char* ws = (char*)d_ws;
    float* wts = (float*)ws;                                   // 128 KB
    f16* xb  = (f16*)(ws + (size_t)(128 << 10));               // 16 MB
    f16* w1t = (f16*)(ws + (size_t)(128 << 10) + (16u << 20)); // 8 MB (per-expert, reused)
    f16* w2t = (f16*)(ws + (size_t)(128 << 10) + (24u << 20)); // 8 MB (per-expert, reused)
    f16* h   = (f16*)(ws + (size_t)(128 << 10) + (32u << 20)); // 64 MB

    const int aux_idx = (out_size == M_TOK * DDIM + 1) ? (M_TOK * DDIM) : -1;
    router_kernel<<<M_TOK / 4, 256, 0, stream>>>(x, Wr, wts, out, aux_idx);
    convert_f16_kernel<<<(M_TOK * DDIM / 4) / 256, 256, 0, stream>>>(x, xb, M_TOK * DDIM / 4);

    for (int e = 0; e < NEXP; ++e) {
        // W1[e]: [D][H] fp32 -> w1t: [H][D] f16
        transpose_f16_kernel<<<dim3(HDIM / 32, DDIM / 32), 256, 0, stream>>>(
            W1 + (size_t)e * DDIM * HDIM, w1t, DDIM, HDIM);
        // h = relu(x @ W1[e] + b1[e])   [8192 x 4096]
        gemm_kernel<0><<<dim3(HDIM / 128, M_TOK / 128), 256, 0, stream>>>(
            xb, w1t, M_TOK, HDIM, DDIM, b1 + (size_t)e * HDIM, h, nullptr, nullptr, e, 0);
        // W2[e]: [H][D] fp32 -> w2t: [D][H] f16
        transpose_f16_kernel<<<dim3(DDIM / 32, HDIM / 32), 256, 0, stream>>>(
            W2 + (size_t)e * HDIM * DDIM, w2t, HDIM, DDIM);
        // out (+)= w_e * (h @ W2[e] + b2[e])   [8192 x 1024]
        gemm_kernel<1><<<dim3(DDIM / 128, M_TOK / 128), 256, 0, stream>>>(
            h, w2t, M_TOK, DDIM, HDIM, b2 + (size_t)e * DDIM, nullptr, out, wts, e, e == 0);
    }
}

// Round 2
// 736.858 us; speedup vs baseline: 1.4339x; 1.4339x over previous
//
#include <hip/hip_runtime.h>
#include <cstdint>
#include <cstddef>

typedef _Float16 f16;
typedef __attribute__((ext_vector_type(8))) f16 f16x8;
typedef __attribute__((ext_vector_type(4))) f16 f16x4;
typedef __attribute__((ext_vector_type(4))) float f32x4;

#define M_TOK 8192
#define DDIM 1024
#define HDIM 4096
#define NEXP 4
#define TOTPAD 16896  // >= 16384 + 4*127, rounded to 128

// async global->LDS, 16B per lane (global address may be per-lane; LDS dest
// must be wave-uniform base + lane*16 — our mapping is exactly that).
__device__ __forceinline__ void async_copy16(const void* g, void* s) {
    __builtin_amdgcn_global_load_lds((__attribute__((address_space(1))) void*)g,
                                     (__attribute__((address_space(3))) void*)s,
                                     16, 0, 0);
}

// ---------------- Router: logits -> top2 softmax weights ------------------
// one wave per token; top2-of-softmax + renorm == softmax over top-2 logits.
__global__ __launch_bounds__(256) void router_kernel(
    const float* __restrict__ x, const float* __restrict__ Wr,
    float* __restrict__ wts, int* __restrict__ top2) {
    __shared__ float wr_s[DDIM * NEXP];
    for (int i = threadIdx.x; i < DDIM * NEXP; i += 256) wr_s[i] = Wr[i];
    __syncthreads();
    const int wave = threadIdx.x >> 6, lane = threadIdx.x & 63;
    const int t = blockIdx.x * 4 + wave;
    float a0 = 0.f, a1 = 0.f, a2 = 0.f, a3 = 0.f;
    const float* xr = x + (size_t)t * DDIM;
    for (int i = 0; i < DDIM; i += 256) {
        const int d = i + lane * 4;
        const float4 v = *(const float4*)(xr + d);
        const float* w0 = &wr_s[d * 4];
        a0 += v.x * w0[0] + v.y * w0[4] + v.z * w0[8]  + v.w * w0[12];
        a1 += v.x * w0[1] + v.y * w0[5] + v.z * w0[9]  + v.w * w0[13];
        a2 += v.x * w0[2] + v.y * w0[6] + v.z * w0[10] + v.w * w0[14];
        a3 += v.x * w0[3] + v.y * w0[7] + v.z * w0[11] + v.w * w0[15];
    }
    for (int off = 32; off > 0; off >>= 1) {
        a0 += __shfl_xor(a0, off, 64);
        a1 += __shfl_xor(a1, off, 64);
        a2 += __shfl_xor(a2, off, 64);
        a3 += __shfl_xor(a3, off, 64);
    }
    if (lane == 0) {
        float lg[4] = {a0, a1, a2, a3};
        int i1 = 0;
        for (int e = 1; e < 4; ++e) if (lg[e] > lg[i1]) i1 = e;
        int i2 = -1;
        for (int e = 0; e < 4; ++e) {
            if (e == i1) continue;
            if (i2 < 0 || lg[e] > lg[i2]) i2 = e;
        }
        const float w1 = 1.0f / (1.0f + expf(lg[i2] - lg[i1]));
        float w[4] = {0.f, 0.f, 0.f, 0.f};
        w[i1] = w1; w[i2] = 1.0f - w1;
        float* o = wts + (size_t)t * 4;
        o[0] = w[0]; o[1] = w[1]; o[2] = w[2]; o[3] = w[3];
        top2[t] = i1 | (i2 << 8);
    }
}

// ---------------- count / offsets / fill (sparse routing lists) -----------
__global__ __launch_bounds__(256) void count_kernel(
    const int* __restrict__ top2, int* __restrict__ meta) {
    __shared__ int lc[4];
    if (threadIdx.x < 4) lc[threadIdx.x] = 0;
    __syncthreads();
    const int t = blockIdx.x * 256 + threadIdx.x;
    const int p = top2[t];
    atomicAdd(&lc[p & 0xff], 1);
    atomicAdd(&lc[(p >> 8) & 0xff], 1);
    __syncthreads();
    if (threadIdx.x < 4) atomicAdd(&meta[threadIdx.x], lc[threadIdx.x]);
}

__global__ void offsets_kernel(int* __restrict__ meta) {
    if (threadIdx.x == 0) {
        int off = 0;
        for (int e = 0; e < 4; ++e) {
            const int c = meta[e];
            const int cp = (c + 127) & ~127;
            meta[4 + e] = cp;   // padded count
            meta[8 + e] = off;  // segment offset
            off += cp;
        }
    }
}

__global__ __launch_bounds__(256) void fill_kernel(
    const int* __restrict__ top2, int* __restrict__ meta,
    int* __restrict__ toklist) {
    __shared__ int lc[4], base[4];
    if (threadIdx.x < 4) lc[threadIdx.x] = 0;
    __syncthreads();
    const int t = blockIdx.x * 256 + threadIdx.x;
    const int p = top2[t];
    const int e1 = p & 0xff, e2 = (p >> 8) & 0xff;
    const int r1 = atomicAdd(&lc[e1], 1);
    const int r2 = atomicAdd(&lc[e2], 1);
    __syncthreads();
    if (threadIdx.x < 4) base[threadIdx.x] = atomicAdd(&meta[12 + threadIdx.x], lc[threadIdx.x]);
    __syncthreads();
    toklist[meta[8 + e1] + base[e1] + r1] = t;
    toklist[meta[8 + e2] + base[e2] + r2] = t;
}

// ---------------- fp32 -> f16 elementwise (x) ------------------------------
__global__ __launch_bounds__(256) void convert_f16_kernel(
    const float* __restrict__ in, f16* __restrict__ out, int n4) {
    const int i = blockIdx.x * 256 + threadIdx.x;
    if (i < n4) {
        const float4 v = ((const float4*)in)[i];
        f16x4 o = {(f16)v.x, (f16)v.y, (f16)v.z, (f16)v.w};
        ((f16x4*)out)[i] = o;
    }
}

// ---------------- fp32 [R][C] -> f16 [C][R] transpose (per z-expert) -------
__global__ __launch_bounds__(256) void transpose_f16_kernel(
    const float* __restrict__ in0, f16* __restrict__ out0, int R, int C) {
    __shared__ float tile[32][33];
    const float* in = in0 + (size_t)blockIdx.z * R * C;
    f16* out = out0 + (size_t)blockIdx.z * R * C;
    const int c0 = blockIdx.x * 32, r0 = blockIdx.y * 32;
    const int tx = threadIdx.x & 31;
    const int ty = threadIdx.x >> 5;  // 0..7
#pragma unroll
    for (int i = 0; i < 32; i += 8)
        tile[ty + i][tx] = in[(size_t)(r0 + ty + i) * C + c0 + tx];
    __syncthreads();
#pragma unroll
    for (int i = 0; i < 32; i += 8)
        out[(size_t)(c0 + ty + i) * R + r0 + tx] = (f16)tile[tx][ty + i];
}

// ---------------- 128x128 GEMM, XOR-swizzled LDS, expert-fused (z) --------
// MODE 0: outH[off+m] = relu(A_gather x BT + b1)  (f16)
// MODE 1: atomicAdd(out[tok[off+m]], w * (h x BT + b2))  (fp32, out pre-zeroed)
// meta==null => dense path: cnt=M_TOK, off=0, identity token map.
template <int MODE>
__global__ __launch_bounds__(256) void gemm_kernel(
    const f16* __restrict__ A, const f16* __restrict__ BT,
    int N, int K,
    const float* __restrict__ bias,
    f16* __restrict__ outH, float* __restrict__ outF,
    const float* __restrict__ wts,
    const int* __restrict__ toklist, const int* __restrict__ meta, int e0) {
    __shared__ __align__(16) f16 As[128 * 64];
    __shared__ __align__(16) f16 Bs[128 * 64];
    const int zz = blockIdx.z;
    const int e = e0 + zz;
    const int m0 = blockIdx.y * 128, n0 = blockIdx.x * 128;

    int cnt = M_TOK, off = 0;
    if (meta) {
        cnt = meta[e];
        const int cp = meta[4 + e];
        off = meta[8 + e];
        if (m0 >= cp) return;
    }

    const f16* BTe = BT + (size_t)zz * N * K;
    const float* be = bias + (size_t)zz * N;

    const int tid = threadIdx.x;
    const int wave = tid >> 6, lane = tid & 63;
    const int wm = wave >> 1, wn = wave & 1;
    const int quad = lane >> 4, l16 = lane & 15;

    f32x4 acc[4][4] = {};

    // staging mapping: round r -> local row lr = r*32 + (tid>>3); lane's 16B
    // chunk position = tid&7, but it FETCHES global chunk (tid&7)^(lr&7) so
    // LDS position p of row lr holds global chunk p^(lr&7) (bank spread)
    // while keeping the lane*16-contiguous LDS dest global_load_lds needs.
    const int lrb = tid >> 3;                       // 0..31
    const int gcoff = (((tid & 7) ^ (lrb & 7)) * 8);  // swizzled k-element offset
    const f16* ga[4];
    const f16* gb[4];
#pragma unroll
    for (int r = 0; r < 4; ++r) {
        const int lr = r * 32 + lrb;
        const int gm = m0 + lr;
        int arow;
        if (MODE == 0) arow = toklist ? toklist[off + gm] : gm;
        else arow = off + gm;
        ga[r] = A + (size_t)arow * K + gcoff;
        gb[r] = BTe + (size_t)(n0 + lr) * K + gcoff;
    }

    const int swl = l16 & 7;
    for (int k0 = 0; k0 < K; k0 += 64) {
#pragma unroll
        for (int r = 0; r < 4; ++r)
            async_copy16(ga[r] + k0, &As[(r * 256 + tid) * 8]);
#pragma unroll
        for (int r = 0; r < 4; ++r)
            async_copy16(gb[r] + k0, &Bs[(r * 256 + tid) * 8]);
        __syncthreads();
#pragma unroll
        for (int kk = 0; kk < 64; kk += 32) {
            const int kc = kk >> 3;  // chunk base: 0 or 4
            f16x8 af[4], bf[4];
#pragma unroll
            for (int i = 0; i < 4; ++i)
                af[i] = *(const f16x8*)&As[(size_t)(wm * 64 + i * 16 + l16) * 64 +
                                           (((kc + quad) ^ swl) << 3)];
#pragma unroll
            for (int j = 0; j < 4; ++j)
                bf[j] = *(const f16x8*)&Bs[(size_t)(wn * 64 + j * 16 + l16) * 64 +
                                           (((kc + quad) ^ swl) << 3)];
#pragma unroll
            for (int i = 0; i < 4; ++i)
#pragma unroll
                for (int j = 0; j < 4; ++j)
                    acc[i][j] = __builtin_amdgcn_mfma_f32_16x16x32_f16(af[i], bf[j], acc[i][j], 0, 0, 0);
        }
        __syncthreads();
    }

    // epilogue: C/D layout col = lane&15, row = quad*4 + reg
#pragma unroll
    for (int i = 0; i < 4; ++i) {
        const int mbase = m0 + wm * 64 + i * 16 + quad * 4;
#pragma unroll
        for (int j = 0; j < 4; ++j) {
            const int n = n0 + wn * 64 + j * 16 + l16;
            const float bv = be[n];
#pragma unroll
            for (int r = 0; r < 4; ++r) {
                const int m = mbase + r;
                float v = acc[i][j][r] + bv;
                if (MODE == 0) {
                    v = v > 0.0f ? v : 0.0f;
                    outH[(size_t)(off + m) * N + n] = (f16)v;
                } else {
                    if (m < cnt) {
                        const int t = toklist ? toklist[off + m] : m;
                        const float w = wts[t * 4 + e];
                        atomicAdd(&outF[(size_t)t * N + n], w * v);
                    }
                }
            }
        }
    }
}

extern "C" void kernel_launch(void* const* d_in, const int* in_sizes, int n_in,
                              void* d_out, int out_size, void* d_ws, size_t ws_size,
                              hipStream_t stream) {
    (void)in_sizes; (void)n_in;
    const float* x  = (const float*)d_in[0];
    const float* Wr = (const float*)d_in[1];
    const float* W1 = (const float*)d_in[2];
    const float* b1 = (const float*)d_in[3];
    const float* W2 = (const float*)d_in[4];
    const float* b2 = (const float*)d_in[5];
    float* out = (float*)d_out;

    char* ws = (char*)d_ws;
    float* wts   = (float*)ws;                    // 128 KB
    int*   meta  = (int*)(ws + (128 << 10));      // 16 ints (4 KB reserved)
    int*   top2  = (int*)(ws + (132 << 10));      // 32 KB
    int*   tokl  = (int*)(ws + (164 << 10));      // 66 KB (reserved to 256 KB)
    f16*   xb    = (f16*)(ws + (256 << 10));      // 16 MB
    const size_t MBs = 1ull << 20;
    const size_t base = (256 << 10) + 16 * MBs;

    const size_t SPARSE_NEED = (256 << 10) + 80 * MBs + (size_t)TOTPAD * HDIM * sizeof(f16);
    const bool sparse = ws_size >= SPARSE_NEED;

    f16 *w1t, *w2t, *h;
    if (sparse) {
        w1t = (f16*)(ws + base);             // 32 MB [E][H][D]
        w2t = (f16*)(ws + base + 32 * MBs);  // 32 MB [E][D][H]
        h   = (f16*)(ws + base + 64 * MBs);  // 138.4 MB (TOTPAD x HDIM)
    } else {
        w1t = (f16*)(ws + base);             // 8 MB, per-expert reuse
        w2t = (f16*)(ws + base + 8 * MBs);   // 8 MB
        h   = (f16*)(ws + base + 16 * MBs);  // 64 MB
    }

    hipMemsetAsync(out, 0, (size_t)out_size * sizeof(float), stream);
    router_kernel<<<M_TOK / 4, 256, 0, stream>>>(x, Wr, wts, top2);
    convert_f16_kernel<<<(M_TOK * DDIM / 4) / 256, 256, 0, stream>>>(x, xb, M_TOK * DDIM / 4);

    if (sparse) {
        hipMemsetAsync(meta, 0, 16 * sizeof(int), stream);
        hipMemsetAsync(tokl, 0, (size_t)TOTPAD * sizeof(int), stream);
        count_kernel<<<M_TOK / 256, 256, 0, stream>>>(top2, meta);
        offsets_kernel<<<1, 64, 0, stream>>>(meta);
        fill_kernel<<<M_TOK / 256, 256, 0, stream>>>(top2, meta, tokl);
        // all-expert weight transposes
        transpose_f16_kernel<<<dim3(HDIM / 32, DDIM / 32, NEXP), 256, 0, stream>>>(W1, w1t, DDIM, HDIM);
        transpose_f16_kernel<<<dim3(DDIM / 32, HDIM / 32, NEXP), 256, 0, stream>>>(W2, w2t, HDIM, DDIM);
        // fused-across-experts sparse GEMMs (early-exit per z on padded count)
        gemm_kernel<0><<<dim3(HDIM / 128, M_TOK / 128, NEXP), 256, 0, stream>>>(
            xb, w1t, HDIM, DDIM, b1, h, nullptr, wts, tokl, meta, 0);
        gemm_kernel<1><<<dim3(DDIM / 128, M_TOK / 128, NEXP), 256, 0, stream>>>(
            h, w2t, DDIM, HDIM, b2, nullptr, out, wts, tokl, meta, 0);
    } else {
        for (int e = 0; e < NEXP; ++e) {
            transpose_f16_kernel<<<dim3(HDIM / 32, DDIM / 32, 1), 256, 0, stream>>>(
                W1 + (size_t)e * DDIM * HDIM, w1t, DDIM, HDIM);
            gemm_kernel<0><<<dim3(HDIM / 128, M_TOK / 128, 1), 256, 0, stream>>>(
                xb, w1t, HDIM, DDIM, b1 + (size_t)e * HDIM, h, nullptr, wts, nullptr, nullptr, e);
            transpose_f16_kernel<<<dim3(DDIM / 32, HDIM / 32, 1), 256, 0, stream>>>(
                W2 + (size_t)e * HDIM * DDIM, w2t, HDIM, DDIM);
            gemm_kernel<1><<<dim3(DDIM / 128, M_TOK / 128, 1), 256, 0, stream>>>(
                h, w2t, DDIM, HDIM, b2 + (size_t)e * DDIM, nullptr, out, wts, nullptr, nullptr, e);
        }
    }
}